// Round 1
// baseline (3186.172 us; speedup 1.0000x reference)
//
#include <hip/hip_runtime.h>
#include <math.h>

#define DM 512          // d_model
#define STOK 32         // tokens per video in transformer (30 frames + 2 expansion)
#define BATCH 256
#define NTOK_V 62       // 30 frame_n + 32 video_n tokens per video for sims
#define NVID_ROWS 15872 // 256*62

// ---------------------------------------------------------------- concat
__global__ __launch_bounds__(256) void k_concat(const float* __restrict__ frames,
                                                const float* __restrict__ expt,
                                                float* __restrict__ X) {
    int row = blockIdx.x;            // 0..8191 = b*32+s
    int b = row >> 5, s = row & 31;
    int t = threadIdx.x;
    const float* src = (s < 30) ? (frames + ((size_t)(b * 30 + s)) * DM)
                                : (expt + (size_t)(s - 30) * DM);
    X[(size_t)row * DM + t]       = src[t];
    X[(size_t)row * DM + t + 256] = src[t + 256];
}

// ---------------------------------------------------------------- GEMM C = A @ B^T (+bias, optional relu)
// A [M,K] row-major, B [N,K] row-major, C [M,N]. M,N multiples of 64; K multiple of 32.
__global__ __launch_bounds__(256) void k_gemm(const float* __restrict__ A,
                                              const float* __restrict__ B,
                                              const float* __restrict__ bias,
                                              float* __restrict__ C,
                                              int M, int N, int K, int relu) {
    __shared__ float As[32][68];   // [k][m], +4 pad keeps 16B alignment & breaks conflicts
    __shared__ float Bs[32][68];
    int t = threadIdx.x;
    int tx = t & 15, ty = t >> 4;
    int lk = (t & 7) << 2;         // k offset for loads
    int lr = t >> 3;               // row 0..31 (and +32)
    size_t row0 = (size_t)blockIdx.y * 64;
    size_t col0 = (size_t)blockIdx.x * 64;
    const float* Ap = A + (row0 + lr) * (size_t)K + lk;
    const float* Bp = B + (col0 + lr) * (size_t)K + lk;
    float acc[4][4] = {{0.f}};
    for (int k0 = 0; k0 < K; k0 += 32) {
        float4 a0 = *(const float4*)(Ap + k0);
        float4 a1 = *(const float4*)(Ap + k0 + (size_t)32 * K);
        float4 b0 = *(const float4*)(Bp + k0);
        float4 b1 = *(const float4*)(Bp + k0 + (size_t)32 * K);
        __syncthreads();
        As[lk + 0][lr] = a0.x; As[lk + 1][lr] = a0.y; As[lk + 2][lr] = a0.z; As[lk + 3][lr] = a0.w;
        As[lk + 0][lr + 32] = a1.x; As[lk + 1][lr + 32] = a1.y; As[lk + 2][lr + 32] = a1.z; As[lk + 3][lr + 32] = a1.w;
        Bs[lk + 0][lr] = b0.x; Bs[lk + 1][lr] = b0.y; Bs[lk + 2][lr] = b0.z; Bs[lk + 3][lr] = b0.w;
        Bs[lk + 0][lr + 32] = b1.x; Bs[lk + 1][lr + 32] = b1.y; Bs[lk + 2][lr + 32] = b1.z; Bs[lk + 3][lr + 32] = b1.w;
        __syncthreads();
#pragma unroll
        for (int k = 0; k < 32; ++k) {
            float4 av = *(const float4*)&As[k][ty << 2];
            float4 bv = *(const float4*)&Bs[k][tx << 2];
            acc[0][0] += av.x * bv.x; acc[0][1] += av.x * bv.y; acc[0][2] += av.x * bv.z; acc[0][3] += av.x * bv.w;
            acc[1][0] += av.y * bv.x; acc[1][1] += av.y * bv.y; acc[1][2] += av.y * bv.z; acc[1][3] += av.y * bv.w;
            acc[2][0] += av.z * bv.x; acc[2][1] += av.z * bv.y; acc[2][2] += av.z * bv.z; acc[2][3] += av.z * bv.w;
            acc[3][0] += av.w * bv.x; acc[3][1] += av.w * bv.y; acc[3][2] += av.w * bv.z; acc[3][3] += av.w * bv.w;
        }
    }
#pragma unroll
    for (int i = 0; i < 4; ++i) {
#pragma unroll
        for (int j = 0; j < 4; ++j) {
            size_t r = row0 + (ty << 2) + i;
            size_t c = col0 + (tx << 2) + j;
            float v = acc[i][j];
            if (bias) v += bias[c];
            if (relu) v = fmaxf(v, 0.f);
            C[r * N + c] = v;
        }
    }
}

// ---------------------------------------------------------------- attention, one block per (b,h)
__global__ __launch_bounds__(256) void k_attn(const float* __restrict__ qkv,
                                              float* __restrict__ att) {
    __shared__ float q[32][65], k[32][65], v[32][65];
    __shared__ float sc[32][33];
    int b = blockIdx.x >> 3, h = blockIdx.x & 7;
    int t = threadIdx.x;
    const float* base = qkv + (size_t)b * 32 * 1536 + h * 64;
    for (int i = t; i < 2048; i += 256) {
        int s = i >> 6, d = i & 63;
        size_t ro = (size_t)s * 1536 + d;
        q[s][d] = base[ro];
        k[s][d] = base[ro + 512];
        v[s][d] = base[ro + 1024];
    }
    __syncthreads();
    // scores (scaled by 1/sqrt(64) = 0.125)
    {
        int r = t >> 3, c0 = (t & 7) << 2;
        float s0 = 0.f, s1 = 0.f, s2 = 0.f, s3 = 0.f;
#pragma unroll 8
        for (int d = 0; d < 64; ++d) {
            float qv = q[r][d];
            s0 += qv * k[c0 + 0][d];
            s1 += qv * k[c0 + 1][d];
            s2 += qv * k[c0 + 2][d];
            s3 += qv * k[c0 + 3][d];
        }
        sc[r][c0 + 0] = s0 * 0.125f;
        sc[r][c0 + 1] = s1 * 0.125f;
        sc[r][c0 + 2] = s2 * 0.125f;
        sc[r][c0 + 3] = s3 * 0.125f;
    }
    __syncthreads();
    if (t < 32) {
        float mx = -1e30f;
        for (int c = 0; c < 32; ++c) mx = fmaxf(mx, sc[t][c]);
        float sum = 0.f;
        for (int c = 0; c < 32; ++c) { float e = expf(sc[t][c] - mx); sc[t][c] = e; sum += e; }
        float inv = 1.f / sum;
        for (int c = 0; c < 32; ++c) sc[t][c] *= inv;
    }
    __syncthreads();
    for (int i = t; i < 2048; i += 256) {
        int s = i >> 6, d = i & 63;
        float acc = 0.f;
#pragma unroll 8
        for (int c = 0; c < 32; ++c) acc += sc[s][c] * v[c][d];
        att[((size_t)b * 32 + s) * DM + h * 64 + d] = acc;
    }
}

// ---------------------------------------------------------------- x = LN(x + y)*w + b, one block per row
__global__ __launch_bounds__(256) void k_addln(float* __restrict__ x,
                                               const float* __restrict__ y,
                                               const float* __restrict__ w,
                                               const float* __restrict__ b) {
    size_t row = blockIdx.x;
    int t = threadIdx.x;
    float v0 = x[row * DM + t] + y[row * DM + t];
    float v1 = x[row * DM + t + 256] + y[row * DM + t + 256];
    float s = v0 + v1;
#pragma unroll
    for (int o = 32; o; o >>= 1) s += __shfl_xor(s, o);
    __shared__ float ss[4], qs[4];
    if ((t & 63) == 0) ss[t >> 6] = s;
    __syncthreads();
    float mean = (ss[0] + ss[1] + ss[2] + ss[3]) * (1.f / 512.f);
    float d0 = v0 - mean, d1 = v1 - mean;
    float qv = d0 * d0 + d1 * d1;
#pragma unroll
    for (int o = 32; o; o >>= 1) qv += __shfl_xor(qv, o);
    if ((t & 63) == 0) qs[t >> 6] = qv;
    __syncthreads();
    float var = (qs[0] + qs[1] + qs[2] + qs[3]) * (1.f / 512.f);
    float inv = 1.f / sqrtf(var + 1e-5f);
    x[row * DM + t]       = d0 * inv * w[t] + b[t];
    x[row * DM + t + 256] = d1 * inv * w[t + 256] + b[t + 256];
}

// ---------------------------------------------------------------- l2 normalize rows of [nrows, 512]
__global__ __launch_bounds__(256) void k_l2rows(const float* __restrict__ in,
                                                float* __restrict__ outp) {
    size_t row = blockIdx.x;
    int t = threadIdx.x;
    float v0 = in[row * DM + t], v1 = in[row * DM + t + 256];
    float q = v0 * v0 + v1 * v1;
#pragma unroll
    for (int o = 32; o; o >>= 1) q += __shfl_xor(q, o);
    __shared__ float qs[4];
    if ((t & 63) == 0) qs[t >> 6] = q;
    __syncthreads();
    float n = sqrtf(qs[0] + qs[1] + qs[2] + qs[3]);
    float sc = 1.f / fmaxf(n, 1e-12f);
    outp[row * DM + t]       = v0 * sc;
    outp[row * DM + t + 256] = v1 * sc;
}

// ---------------------------------------------------------------- build TOK: per video j, 30 l2'd frame rows + 32 l2'd video rows
__global__ __launch_bounds__(256) void k_build_tok(const float* __restrict__ frames,
                                                   const float* __restrict__ X,
                                                   float* __restrict__ TOK) {
    int rid = blockIdx.x;            // 0..15871
    int j = rid / NTOK_V, tt = rid % NTOK_V;
    int t = threadIdx.x;
    const float* src = (tt < 30) ? frames + ((size_t)j * 30 + tt) * DM
                                 : X + ((size_t)j * 32 + (tt - 30)) * DM;
    float v0 = src[t], v1 = src[t + 256];
    float q = v0 * v0 + v1 * v1;
#pragma unroll
    for (int o = 32; o; o >>= 1) q += __shfl_xor(q, o);
    __shared__ float qs[4];
    if ((t & 63) == 0) qs[t >> 6] = q;
    __syncthreads();
    float n = sqrtf(qs[0] + qs[1] + qs[2] + qs[3]);
    float sc = 1.f / fmaxf(n, 1e-12f);
    TOK[(size_t)rid * DM + t]       = v0 * sc;
    TOK[(size_t)rid * DM + t + 256] = v1 * sc;
}

// ---------------------------------------------------------------- max-reduce DOTS -> sims
__global__ __launch_bounds__(256) void k_sim(const float* __restrict__ dots,
                                             float* __restrict__ out) {
    int i = blockIdx.x;
    int j = threadIdx.x;
    const float* p = dots + (size_t)i * NVID_ROWS + (size_t)j * NTOK_V;
    float mf = -1e30f, mv = -1e30f;
#pragma unroll
    for (int tt = 0; tt < 30; ++tt) mf = fmaxf(mf, p[tt]);
#pragma unroll
    for (int tt = 30; tt < 62; ++tt) mv = fmaxf(mv, p[tt]);
    int o = i * 256 + j;
    out[o]          = mf + mv;
    out[65536 + o]  = mf;
    out[131072 + o] = mv;
}

// ---------------------------------------------------------------- launcher
extern "C" void kernel_launch(void* const* d_in, const int* in_sizes, int n_in,
                              void* d_out, int out_size, void* d_ws, size_t ws_size,
                              hipStream_t stream) {
    const float* text   = (const float*)d_in[0];
    const float* frames = (const float*)d_in[1];
    const float* expt   = (const float*)d_in[2];
    const float* Wqkv   = (const float*)d_in[3];
    const float* bqkv   = (const float*)d_in[4];
    const float* Wo     = (const float*)d_in[5];
    const float* bo     = (const float*)d_in[6];
    const float* ln1w   = (const float*)d_in[7];
    const float* ln1b   = (const float*)d_in[8];
    const float* W1     = (const float*)d_in[9];
    const float* b1     = (const float*)d_in[10];
    const float* W2     = (const float*)d_in[11];
    const float* b2     = (const float*)d_in[12];
    const float* ln2w   = (const float*)d_in[13];
    const float* ln2b   = (const float*)d_in[14];
    float* out = (float*)d_out;

    float* ws = (float*)d_ws;
    float* X    = ws;                    // 4,194,304 floats  [8192,512]
    float* BIG  = ws + 4194304;          // 16,777,216 floats [8192,2048] (also QKV [8192,1536], DOTS)
    float* ATT  = ws + 20971520;         // 4,194,304 floats  [8192,512]
    float* PROJ = ws + 25165824;         // 4,194,304 floats  [8192,512]
    float* QHAT = ws + 29360128;         // 131,072 floats    [256,512]
    float* TOK  = ATT;                   // 8,126,464 floats — aliases ATT+PROJ (free post-transformer)
    float* DOTS = BIG;                   // 4,063,232 floats — aliases BIG

    k_concat<<<8192, 256, 0, stream>>>(frames, expt, X);

    for (int l = 0; l < 4; ++l) {
        const float* Wqkv_l = Wqkv + (size_t)l * 1536 * 512;
        const float* bqkv_l = bqkv + (size_t)l * 1536;
        const float* Wo_l   = Wo + (size_t)l * 512 * 512;
        const float* bo_l   = bo + (size_t)l * 512;
        const float* W1_l   = W1 + (size_t)l * 2048 * 512;
        const float* b1_l   = b1 + (size_t)l * 2048;
        const float* W2_l   = W2 + (size_t)l * 512 * 2048;
        const float* b2_l   = b2 + (size_t)l * 512;

        k_gemm<<<dim3(24, 128), 256, 0, stream>>>(X, Wqkv_l, bqkv_l, BIG, 8192, 1536, 512, 0);
        k_attn<<<2048, 256, 0, stream>>>(BIG, ATT);
        k_gemm<<<dim3(8, 128), 256, 0, stream>>>(ATT, Wo_l, bo_l, PROJ, 8192, 512, 512, 0);
        k_addln<<<8192, 256, 0, stream>>>(X, PROJ, ln1w + (size_t)l * 512, ln1b + (size_t)l * 512);
        k_gemm<<<dim3(32, 128), 256, 0, stream>>>(X, W1_l, b1_l, BIG, 8192, 2048, 512, 1);
        k_gemm<<<dim3(8, 128), 256, 0, stream>>>(BIG, W2_l, b2_l, PROJ, 8192, 512, 2048, 0);
        k_addln<<<8192, 256, 0, stream>>>(X, PROJ, ln2w + (size_t)l * 512, ln2b + (size_t)l * 512);
    }

    k_l2rows<<<256, 256, 0, stream>>>(text, QHAT);
    k_build_tok<<<NVID_ROWS, 256, 0, stream>>>(frames, X, TOK);
    k_gemm<<<dim3(248, 4), 256, 0, stream>>>(QHAT, TOK, nullptr, DOTS, 256, NVID_ROWS, 512, 0);
    k_sim<<<256, 256, 0, stream>>>(DOTS, out);
}

// Round 2
// 781.599 us; speedup vs baseline: 4.0765x; 4.0765x over previous
//
#include <hip/hip_runtime.h>
#include <math.h>

#define DM 512
#define NTOK_V 62
#define NVID 256

typedef _Float16 h16;
typedef __attribute__((ext_vector_type(8))) _Float16 h16x8;
typedef __attribute__((ext_vector_type(4))) float f32x4;

// async global->LDS, 16B per lane, dest = wave-uniform base + lane*16
__device__ __forceinline__ void ldsload16(const void* g, void* l) {
    __builtin_amdgcn_global_load_lds(
        (const __attribute__((address_space(1))) unsigned int*)g,
        (__attribute__((address_space(3))) unsigned int*)l, 16, 0, 0);
}

// ---------------------------------------------------------------- fp32 -> fp16 convert (8 elems/thread)
__global__ __launch_bounds__(256) void k_cvt(const float* __restrict__ in,
                                             h16* __restrict__ outp, int n8) {
    int i = blockIdx.x * 256 + threadIdx.x;
    if (i >= n8) return;
    float4 a = ((const float4*)in)[i * 2];
    float4 b = ((const float4*)in)[i * 2 + 1];
    h16x8 h;
    h[0] = (h16)a.x; h[1] = (h16)a.y; h[2] = (h16)a.z; h[3] = (h16)a.w;
    h[4] = (h16)b.x; h[5] = (h16)b.y; h[6] = (h16)b.z; h[7] = (h16)b.w;
    ((h16x8*)outp)[i] = h;
}

// ---------------------------------------------------------------- concat -> fp16 X
__global__ __launch_bounds__(256) void k_concat_h(const float* __restrict__ frames,
                                                  const float* __restrict__ expt,
                                                  h16* __restrict__ X) {
    int row = blockIdx.x;
    int b = row >> 5, s = row & 31;
    int t = threadIdx.x;
    const float* src = (s < 30) ? (frames + ((size_t)(b * 30 + s)) * DM)
                                : (expt + (size_t)(s - 30) * DM);
    X[(size_t)row * DM + t]       = (h16)src[t];
    X[(size_t)row * DM + t + 256] = (h16)src[t + 256];
}

// ---------------------------------------------------------------- MFMA fp16 GEMM  C = A @ B^T (+bias, relu)
// A [M,K] fp16 row-major, B [N,K] fp16 row-major, C [M,N] fp16.
// M,N % 128 == 0, K % 32 == 0. 256 threads = 4 waves in 2x2, each wave 64x64 out.
// LDS tile layout per buffer: [row_group g=0..7][lane] 16B: element (row=g*16+r, k=kc*8+e)
// at byte g*1024 + (kc*16+r)*16 + e*2  -> both global_load_lds dest (linear in lane)
// and ds_read_b128 fragment reads (16 lanes contiguous 256B) are conflict-free.
template<int RELU>
__global__ __launch_bounds__(256, 2) void k_hgemm(const h16* __restrict__ A,
                                                  const h16* __restrict__ B,
                                                  const float* __restrict__ bias,
                                                  h16* __restrict__ C,
                                                  int M, int N, int K) {
    __shared__ char smem[32768];   // 2 buffers x (A 8KB + B 8KB)
    const int t = threadIdx.x;
    const int w = t >> 6, lane = t & 63;
    const int wr = w >> 1, wc = w & 1;
    const int kc = lane >> 4, rr = lane & 15;
    const size_t row0 = (size_t)blockIdx.y * 128;
    const size_t col0 = (size_t)blockIdx.x * 128;

    const h16* gA = A + (row0 + (w << 5) + rr) * (size_t)K + (kc << 3);
    const h16* gB = B + (col0 + (w << 5) + rr) * (size_t)K + (kc << 3);

    f32x4 acc[4][4];
#pragma unroll
    for (int m = 0; m < 4; ++m)
#pragma unroll
        for (int n = 0; n < 4; ++n) acc[m][n] = (f32x4){0.f, 0.f, 0.f, 0.f};

    const int nt = K >> 5;

#define STAGE(buf, k0)                                                  \
    {                                                                   \
        char* sA = smem + (buf) * 16384 + (w << 11);                    \
        char* sB = sA + 8192;                                           \
        ldsload16(gA + (k0), sA);                                       \
        ldsload16(gA + (k0) + (size_t)16 * K, sA + 1024);               \
        ldsload16(gB + (k0), sB);                                       \
        ldsload16(gB + (k0) + (size_t)16 * K, sB + 1024);               \
    }

    STAGE(0, 0)
    __syncthreads();
    for (int it = 0; it < nt; ++it) {
        int cur = it & 1;
        if (it + 1 < nt) STAGE(cur ^ 1, (it + 1) << 5)
        const char* bA = smem + cur * 16384;
        const char* bB = bA + 8192;
        h16x8 af[4], bf[4];
#pragma unroll
        for (int m = 0; m < 4; ++m)
            af[m] = *(const h16x8*)(bA + (wr * 4 + m) * 1024 + lane * 16);
#pragma unroll
        for (int n = 0; n < 4; ++n)
            bf[n] = *(const h16x8*)(bB + (wc * 4 + n) * 1024 + lane * 16);
#pragma unroll
        for (int m = 0; m < 4; ++m)
#pragma unroll
            for (int n = 0; n < 4; ++n)
                acc[m][n] = __builtin_amdgcn_mfma_f32_16x16x32_f16(af[m], bf[n], acc[m][n], 0, 0, 0);
        __syncthreads();
    }
#undef STAGE

    // C/D layout: col = lane&15, row = (lane>>4)*4 + reg   [m89/m91-verified]
#pragma unroll
    for (int n = 0; n < 4; ++n) {
        size_t col = col0 + wc * 64 + n * 16 + (lane & 15);
        float bv = bias ? bias[col] : 0.f;
#pragma unroll
        for (int m = 0; m < 4; ++m) {
            size_t rbase = row0 + wr * 64 + m * 16 + ((lane >> 4) << 2);
#pragma unroll
            for (int j = 0; j < 4; ++j) {
                float v = acc[m][n][j] + bv;
                if (RELU) v = fmaxf(v, 0.f);
                C[(rbase + j) * (size_t)N + col] = (h16)v;
            }
        }
    }
}

// ---------------------------------------------------------------- attention, one block per (b,h), fp16 io
__global__ __launch_bounds__(256) void k_attn_h(const h16* __restrict__ qkv,
                                                h16* __restrict__ att) {
    __shared__ float q[32][65], k[32][65], v[32][65];
    __shared__ float sc[32][33];
    int b = blockIdx.x >> 3, h = blockIdx.x & 7;
    int t = threadIdx.x;
    const h16* base = qkv + (size_t)b * 32 * 1536 + h * 64;
    for (int i = t; i < 2048; i += 256) {
        int s = i >> 6, d = i & 63;
        size_t ro = (size_t)s * 1536 + d;
        q[s][d] = (float)base[ro];
        k[s][d] = (float)base[ro + 512];
        v[s][d] = (float)base[ro + 1024];
    }
    __syncthreads();
    {
        int r = t >> 3, c0 = (t & 7) << 2;
        float s0 = 0.f, s1 = 0.f, s2 = 0.f, s3 = 0.f;
#pragma unroll 8
        for (int d = 0; d < 64; ++d) {
            float qv = q[r][d];
            s0 += qv * k[c0 + 0][d];
            s1 += qv * k[c0 + 1][d];
            s2 += qv * k[c0 + 2][d];
            s3 += qv * k[c0 + 3][d];
        }
        sc[r][c0 + 0] = s0 * 0.125f;
        sc[r][c0 + 1] = s1 * 0.125f;
        sc[r][c0 + 2] = s2 * 0.125f;
        sc[r][c0 + 3] = s3 * 0.125f;
    }
    __syncthreads();
    {   // wave-parallel softmax: 8 lanes per row
        int r = t >> 3, c0 = (t & 7) << 2;
        float a0 = sc[r][c0], a1 = sc[r][c0 + 1], a2 = sc[r][c0 + 2], a3 = sc[r][c0 + 3];
        float mx = fmaxf(fmaxf(a0, a1), fmaxf(a2, a3));
        mx = fmaxf(mx, __shfl_xor(mx, 1));
        mx = fmaxf(mx, __shfl_xor(mx, 2));
        mx = fmaxf(mx, __shfl_xor(mx, 4));
        float e0 = expf(a0 - mx), e1 = expf(a1 - mx), e2 = expf(a2 - mx), e3 = expf(a3 - mx);
        float sm = e0 + e1 + e2 + e3;
        sm += __shfl_xor(sm, 1);
        sm += __shfl_xor(sm, 2);
        sm += __shfl_xor(sm, 4);
        float inv = 1.f / sm;
        sc[r][c0] = e0 * inv; sc[r][c0 + 1] = e1 * inv; sc[r][c0 + 2] = e2 * inv; sc[r][c0 + 3] = e3 * inv;
    }
    __syncthreads();
    for (int i = t; i < 2048; i += 256) {
        int s = i >> 6, d = i & 63;
        float acc = 0.f;
#pragma unroll 8
        for (int c = 0; c < 32; ++c) acc += sc[s][c] * v[c][d];
        att[((size_t)b * 32 + s) * DM + h * 64 + d] = (h16)acc;
    }
}

// ---------------------------------------------------------------- x = LN(x + y)*w + b  (fp16 io, fp32 math)
__global__ __launch_bounds__(256) void k_addln_h(h16* __restrict__ x,
                                                 const h16* __restrict__ y,
                                                 const float* __restrict__ w,
                                                 const float* __restrict__ b) {
    size_t row = blockIdx.x;
    int t = threadIdx.x;
    float v0 = (float)x[row * DM + t] + (float)y[row * DM + t];
    float v1 = (float)x[row * DM + t + 256] + (float)y[row * DM + t + 256];
    float s = v0 + v1;
#pragma unroll
    for (int o = 32; o; o >>= 1) s += __shfl_xor(s, o);
    __shared__ float ss[4], qs[4];
    if ((t & 63) == 0) ss[t >> 6] = s;
    __syncthreads();
    float mean = (ss[0] + ss[1] + ss[2] + ss[3]) * (1.f / 512.f);
    float d0 = v0 - mean, d1 = v1 - mean;
    float qv = d0 * d0 + d1 * d1;
#pragma unroll
    for (int o = 32; o; o >>= 1) qv += __shfl_xor(qv, o);
    if ((t & 63) == 0) qs[t >> 6] = qv;
    __syncthreads();
    float var = (qs[0] + qs[1] + qs[2] + qs[3]) * (1.f / 512.f);
    float inv = 1.f / sqrtf(var + 1e-5f);
    x[row * DM + t]       = (h16)(d0 * inv * w[t] + b[t]);
    x[row * DM + t + 256] = (h16)(d1 * inv * w[t + 256] + b[t + 256]);
}

// ---------------------------------------------------------------- l2 rows: f32 in -> f16 out
__global__ __launch_bounds__(256) void k_l2rows_h(const float* __restrict__ in,
                                                  h16* __restrict__ outp) {
    size_t row = blockIdx.x;
    int t = threadIdx.x;
    float v0 = in[row * DM + t], v1 = in[row * DM + t + 256];
    float q = v0 * v0 + v1 * v1;
#pragma unroll
    for (int o = 32; o; o >>= 1) q += __shfl_xor(q, o);
    __shared__ float qs[4];
    if ((t & 63) == 0) qs[t >> 6] = q;
    __syncthreads();
    float n = sqrtf(qs[0] + qs[1] + qs[2] + qs[3]);
    float sc = 1.f / fmaxf(n, 1e-12f);
    outp[row * DM + t]       = (h16)(v0 * sc);
    outp[row * DM + t + 256] = (h16)(v1 * sc);
}

// ---------------------------------------------------------------- TOK: per video j, 30 l2'd frames + 32 l2'd video tokens
__global__ __launch_bounds__(256) void k_build_tok_h(const float* __restrict__ frames,
                                                     const h16* __restrict__ X,
                                                     h16* __restrict__ TOK) {
    int rid = blockIdx.x;
    int j = rid / NTOK_V, tt = rid % NTOK_V;
    int t = threadIdx.x;
    float v0, v1;
    if (tt < 30) {
        const float* src = frames + ((size_t)j * 30 + tt) * DM;
        v0 = src[t]; v1 = src[t + 256];
    } else {
        const h16* src = X + ((size_t)j * 32 + (tt - 30)) * DM;
        v0 = (float)src[t]; v1 = (float)src[t + 256];
    }
    float q = v0 * v0 + v1 * v1;
#pragma unroll
    for (int o = 32; o; o >>= 1) q += __shfl_xor(q, o);
    __shared__ float qs[4];
    if ((t & 63) == 0) qs[t >> 6] = q;
    __syncthreads();
    float n = sqrtf(qs[0] + qs[1] + qs[2] + qs[3]);
    float sc = 1.f / fmaxf(n, 1e-12f);
    TOK[(size_t)rid * DM + t]       = (h16)(v0 * sc);
    TOK[(size_t)rid * DM + t + 256] = (h16)(v1 * sc);
}

// ---------------------------------------------------------------- max-reduce: dots [256 query][15872] -> sims
__global__ __launch_bounds__(256) void k_sim_h(const h16* __restrict__ dots,
                                               float* __restrict__ out) {
    int i = blockIdx.x;          // query
    int j = threadIdx.x;         // video
    const h16* p = dots + (size_t)i * 15872 + (size_t)j * NTOK_V;
    float mf = -1e30f, mv = -1e30f;
#pragma unroll
    for (int tt = 0; tt < 30; ++tt) mf = fmaxf(mf, (float)p[tt]);
#pragma unroll
    for (int tt = 30; tt < 62; ++tt) mv = fmaxf(mv, (float)p[tt]);
    int o = i * 256 + j;
    out[o]          = mf + mv;
    out[65536 + o]  = mf;
    out[131072 + o] = mv;
}

// ---------------------------------------------------------------- launcher
extern "C" void kernel_launch(void* const* d_in, const int* in_sizes, int n_in,
                              void* d_out, int out_size, void* d_ws, size_t ws_size,
                              hipStream_t stream) {
    const float* text   = (const float*)d_in[0];
    const float* frames = (const float*)d_in[1];
    const float* expt   = (const float*)d_in[2];
    const float* Wqkv   = (const float*)d_in[3];
    const float* bqkv   = (const float*)d_in[4];
    const float* Wo     = (const float*)d_in[5];
    const float* bo     = (const float*)d_in[6];
    const float* ln1w   = (const float*)d_in[7];
    const float* ln1b   = (const float*)d_in[8];
    const float* W1     = (const float*)d_in[9];
    const float* b1     = (const float*)d_in[10];
    const float* W2     = (const float*)d_in[11];
    const float* b2     = (const float*)d_in[12];
    const float* ln2w   = (const float*)d_in[13];
    const float* ln2b   = (const float*)d_in[14];
    float* out = (float*)d_out;

    char* wsb = (char*)d_ws;
    const size_t MB = 1024 * 1024;
    h16* Xh    = (h16*)(wsb);              // 8 MB   [8192,512]
    h16* PROJh = (h16*)(wsb + 8 * MB);     // 8 MB   [8192,512]
    h16* ATTh  = (h16*)(wsb + 16 * MB);    // 8 MB   [8192,512]
    h16* FFh   = (h16*)(wsb + 24 * MB);    // 32 MB  [8192,2048] (also QKV [8192,1536])
    h16* TOKh  = (h16*)(wsb + 24 * MB);    // alias FF region: 15.5 MB [15872,512]
    h16* DOTSh = (h16*)(wsb + 40 * MB);    // alias FF region: 7.75 MB [256,15872]
    h16* Wh    = (h16*)(wsb + 58 * MB);    // 24 MB all weights fp16
    h16* QHATh = (h16*)(wsb + 84 * MB);    // 0.25 MB [256,512]

    h16* Whqkv = Wh;                       // 4*1536*512
    h16* Who   = Whqkv + 3145728;          // 4*512*512
    h16* Wh1   = Who + 1048576;            // 4*2048*512
    h16* Wh2   = Wh1 + 4194304;            // 4*2048*512

    k_cvt<<<1536, 256, 0, stream>>>(Wqkv, Whqkv, 393216);
    k_cvt<<<512,  256, 0, stream>>>(Wo,   Who,   131072);
    k_cvt<<<2048, 256, 0, stream>>>(W1,   Wh1,   524288);
    k_cvt<<<2048, 256, 0, stream>>>(W2,   Wh2,   524288);
    k_concat_h<<<8192, 256, 0, stream>>>(frames, expt, Xh);

    for (int l = 0; l < 4; ++l) {
        k_hgemm<0><<<dim3(12, 64), 256, 0, stream>>>(Xh, Whqkv + (size_t)l * 786432,
                                                     bqkv + (size_t)l * 1536, FFh, 8192, 1536, 512);
        k_attn_h<<<2048, 256, 0, stream>>>(FFh, ATTh);
        k_hgemm<0><<<dim3(4, 64), 256, 0, stream>>>(ATTh, Who + (size_t)l * 262144,
                                                    bo + (size_t)l * 512, PROJh, 8192, 512, 512);
        k_addln_h<<<8192, 256, 0, stream>>>(Xh, PROJh, ln1w + (size_t)l * 512, ln1b + (size_t)l * 512);
        k_hgemm<1><<<dim3(16, 64), 256, 0, stream>>>(Xh, Wh1 + (size_t)l * 1048576,
                                                     b1 + (size_t)l * 2048, FFh, 8192, 2048, 512);
        k_hgemm<0><<<dim3(4, 64), 256, 0, stream>>>(FFh, Wh2 + (size_t)l * 1048576,
                                                    b2 + (size_t)l * 512, PROJh, 8192, 512, 2048);
        k_addln_h<<<8192, 256, 0, stream>>>(Xh, PROJh, ln2w + (size_t)l * 512, ln2b + (size_t)l * 512);
    }

    k_l2rows_h<<<256, 256, 0, stream>>>(text, QHATh);
    k_build_tok_h<<<NVID * NTOK_V, 256, 0, stream>>>(frames, Xh, TOKh);
    k_hgemm<0><<<dim3(124, 2), 256, 0, stream>>>(QHATh, TOKh, nullptr, DOTSh, 256, 15872, 512);
    k_sim_h<<<256, 256, 0, stream>>>(DOTSh, out);
}